// Round 3
// baseline (46.480 us; speedup 1.0000x reference)
//
#include <hip/hip_runtime.h>

// LocalDE: im2col patches (C=3,K=3 -> D=27) then all upper-triangular
// pairwise products (378) per position. Output [B*L, 378] fp32, 186 MB.
// Write-BW bound. R3: 2 positions per wave -> 189 float4 stores per wave
// (16B-aligned since 2*378*4 = 3024 = 189*16), nontemporal via clang
// ext_vector_type (HIP float4 class is rejected by the builtin).

#define B_    32
#define C_    3
#define H_    64
#define W_    64
#define HOUT  62
#define WOUT  62
#define L_    (HOUT * WOUT)   // 3844
#define D_    27
#define NPAIR 378             // D*(D+1)/2
#define NQ4   189             // float4 words per 2 positions (756/4)
#define NPOS  (B_ * L_)       // 123008, divisible by 8

typedef float f32x4 __attribute__((ext_vector_type(4)));

__global__ __launch_bounds__(256) void localde_kernel(
    const float* __restrict__ x, float* __restrict__ out) {
  __shared__ unsigned int tab[NPAIR];  // pair -> (i | j<<8)
  __shared__ float pbuf[8][28];        // 8 positions/block, 27 + pad

  const int tid  = threadIdx.x;
  const int lane = tid & 63;
  const int wv   = tid >> 6;

  // Pair-index table, once per block (378 entries, <=2 per thread).
  for (int t = tid; t < NPAIR; t += 256) {
    int i = 0, s = 0;
    while (s + (D_ - i) <= t) { s += (D_ - i); ++i; }
    int j = i + (t - s);
    tab[t] = (unsigned)i | ((unsigned)j << 8);
  }

  // Stage 8 patches (27 floats each = 216 loads) across the block.
  if (tid < 8 * D_) {
    int pos  = tid / D_;
    int elem = tid - pos * D_;
    int gidx = blockIdx.x * 8 + pos;
    int b  = gidx / L_;
    int l  = gidx - b * L_;
    int oh = l / WOUT;
    int ow = l - oh * WOUT;
    int c  = elem / 9;
    int r  = elem - c * 9;
    int ki = r / 3;
    int kj = r - ki * 3;
    pbuf[pos][elem] = x[((b * C_ + c) * H_ + oh + ki) * W_ + ow + kj];
  }
  __syncthreads();

  // Each wave emits 189 float4 covering 2 consecutive positions.
  const int g0 = blockIdx.x * 8 + wv * 2;          // even
  f32x4* __restrict__ outp = (f32x4*)(out + (size_t)g0 * NPAIR);
  const float* __restrict__ pb = &pbuf[wv * 2][0]; // [2][28] contiguous

#pragma unroll
  for (int t = 0; t < 3; ++t) {
    int q = lane + t * 64;
    if (q < NQ4) {
      f32x4 v;
#pragma unroll
      for (int k = 0; k < 4; ++k) {
        int e  = 4 * q + k;
        int hi = (e >= NPAIR) ? 1 : 0;          // straddle into position g0+1
        int ee = e - hi * NPAIR;
        unsigned tw = tab[ee];
        const float* pp = pb + hi * 28;
        v[k] = pp[tw & 255u] * pp[(tw >> 8) & 255u];
      }
      __builtin_nontemporal_store(v, &outp[q]);
    }
  }
}

extern "C" void kernel_launch(void* const* d_in, const int* in_sizes, int n_in,
                              void* d_out, int out_size, void* d_ws, size_t ws_size,
                              hipStream_t stream) {
  const float* x = (const float*)d_in[0];
  float* out = (float*)d_out;
  const int grid = NPOS / 8;  // 15376 blocks, 8 positions each
  localde_kernel<<<grid, 256, 0, stream>>>(x, out);
}

// Round 4
// 35.161 us; speedup vs baseline: 1.3219x; 1.3219x over previous
//
#include <hip/hip_runtime.h>

// LocalDE: im2col patches (C=3,K=3 -> D=27) then all upper-triangular
// pairwise products (378) per position. Output [B*L, 378] fp32, 186 MB.
// Write-BW bound. R4: R3 minus nontemporal (A/B on the nt bit) —
// 2 positions per wave -> 189 plain float4 stores per wave, 16B-aligned.

#define B_    32
#define C_    3
#define H_    64
#define W_    64
#define HOUT  62
#define WOUT  62
#define L_    (HOUT * WOUT)   // 3844
#define D_    27
#define NPAIR 378             // D*(D+1)/2
#define NQ4   189             // float4 words per 2 positions (756/4)
#define NPOS  (B_ * L_)       // 123008, divisible by 8

typedef float f32x4 __attribute__((ext_vector_type(4)));

__global__ __launch_bounds__(256) void localde_kernel(
    const float* __restrict__ x, float* __restrict__ out) {
  __shared__ unsigned int tab[NPAIR];  // pair -> (i | j<<8)
  __shared__ float pbuf[8][28];        // 8 positions/block, 27 + pad

  const int tid  = threadIdx.x;
  const int lane = tid & 63;
  const int wv   = tid >> 6;

  // Pair-index table, once per block (378 entries, <=2 per thread).
  for (int t = tid; t < NPAIR; t += 256) {
    int i = 0, s = 0;
    while (s + (D_ - i) <= t) { s += (D_ - i); ++i; }
    int j = i + (t - s);
    tab[t] = (unsigned)i | ((unsigned)j << 8);
  }

  // Stage 8 patches (27 floats each = 216 loads) across the block.
  if (tid < 8 * D_) {
    int pos  = tid / D_;
    int elem = tid - pos * D_;
    int gidx = blockIdx.x * 8 + pos;
    int b  = gidx / L_;
    int l  = gidx - b * L_;
    int oh = l / WOUT;
    int ow = l - oh * WOUT;
    int c  = elem / 9;
    int r  = elem - c * 9;
    int ki = r / 3;
    int kj = r - ki * 3;
    pbuf[pos][elem] = x[((b * C_ + c) * H_ + oh + ki) * W_ + ow + kj];
  }
  __syncthreads();

  // Each wave emits 189 float4 covering 2 consecutive positions.
  const int g0 = blockIdx.x * 8 + wv * 2;          // even
  f32x4* __restrict__ outp = (f32x4*)(out + (size_t)g0 * NPAIR);
  const float* __restrict__ pb = &pbuf[wv * 2][0]; // [2][28] contiguous

#pragma unroll
  for (int t = 0; t < 3; ++t) {
    int q = lane + t * 64;
    if (q < NQ4) {
      f32x4 v;
#pragma unroll
      for (int k = 0; k < 4; ++k) {
        int e  = 4 * q + k;
        int hi = (e >= NPAIR) ? 1 : 0;          // straddle into position g0+1
        int ee = e - hi * NPAIR;
        unsigned tw = tab[ee];
        const float* pp = pb + hi * 28;
        v[k] = pp[tw & 255u] * pp[(tw >> 8) & 255u];
      }
      outp[q] = v;
    }
  }
}

extern "C" void kernel_launch(void* const* d_in, const int* in_sizes, int n_in,
                              void* d_out, int out_size, void* d_ws, size_t ws_size,
                              hipStream_t stream) {
  const float* x = (const float*)d_in[0];
  float* out = (float*)d_out;
  const int grid = NPOS / 8;  // 15376 blocks, 8 positions each
  localde_kernel<<<grid, 256, 0, stream>>>(x, out);
}